// Round 1
// baseline (114.599 us; speedup 1.0000x reference)
//
#include <hip/hip_runtime.h>

#define BATCH 8
#define CH 256

// ---------------------------------------------------------------------------
// Kernel A: per-pixel channel dot of x0 (128x128) with com_w0/com_w1, then
// 4x4 average pool + bias + relu -> m1, m2  [8,32,32].
// Valid because pool and 1x1-conv are both linear and commute; bias/relu after.
// Block = 512 threads = 4 rows of 128 pixels; grid = 8 b * 32 row-groups = 256.
// ---------------------------------------------------------------------------
__global__ __launch_bounds__(512)
void dot_pool_kernel(const float* __restrict__ x0,
                     const float* __restrict__ w0, const float* __restrict__ b0,
                     const float* __restrict__ w1, const float* __restrict__ b1,
                     float* __restrict__ m1, float* __restrict__ m2) {
    int blk = blockIdx.x;          // 0..255
    int b   = blk >> 5;            // 8 batches, 32 blocks each
    int pbase = (blk & 31) * 512;  // pixel offset within 128x128 image
    int t = threadIdx.x;           // 0..511
    int p = pbase + t;             // pixel id in [0,16384)

    const float* xb = x0 + b * (CH * 16384) + p;
    float a1 = 0.f, a2 = 0.f;
#pragma unroll 16
    for (int c = 0; c < CH; ++c) {
        float v = xb[c * 16384];
        a1 += v * w0[c];
        a2 += v * w1[c];
    }

    __shared__ float s1[512];
    __shared__ float s2[512];
    s1[t] = a1; s2[t] = a2;
    __syncthreads();

    if (t < 32) {
        // pooled output pixel: h = blk&31 (4 rows per block), w = t
        float t1 = 0.f, t2 = 0.f;
#pragma unroll
        for (int r = 0; r < 4; ++r)
#pragma unroll
            for (int j = 0; j < 4; ++j) {
                t1 += s1[r * 128 + t * 4 + j];
                t2 += s2[r * 128 + t * 4 + j];
            }
        int h = blk & 31;
        float r1 = fmaxf(t1 * 0.0625f + b0[0], 0.f);
        float r2 = fmaxf(t2 * 0.0625f + b1[0], 0.f);
        m1[b * 1024 + h * 32 + t] = r1;
        m2[b * 1024 + h * 32 + t] = r2;
    }
}

// ---------------------------------------------------------------------------
// Kernel B: two 3x3 convs (256ch -> 1, pad=1) + relu on x2 [8,256,32,32].
// Block = 256 threads = 8 channel-groups x 32 x-positions, one (b, y) per block.
// ---------------------------------------------------------------------------
__global__ __launch_bounds__(256)
void conv3x3_kernel(const float* __restrict__ x2,
                    const float* __restrict__ w0, const float* __restrict__ b0,
                    const float* __restrict__ w1, const float* __restrict__ b1,
                    float* __restrict__ c1, float* __restrict__ c2) {
    int y = blockIdx.x;            // 0..31
    int b = blockIdx.y;            // 0..7
    int x  = threadIdx.x & 31;
    int cg = threadIdx.x >> 5;     // 8 groups of 32 channels

    const float* xb = x2 + b * (CH * 1024);
    float a1 = 0.f, a2 = 0.f;

    for (int ci = 0; ci < 32; ++ci) {
        int c = cg * 32 + ci;
        const float* xc = xb + c * 1024;
        const float* wc0 = w0 + c * 9;
        const float* wc1 = w1 + c * 9;
#pragma unroll
        for (int dy = -1; dy <= 1; ++dy) {
            int yy = y + dy;
            bool yok = (unsigned)yy < 32u;
#pragma unroll
            for (int dx = -1; dx <= 1; ++dx) {
                int xx = x + dx;
                bool ok = yok && ((unsigned)xx < 32u);
                float v = ok ? xc[yy * 32 + xx] : 0.f;
                int k = (dy + 1) * 3 + (dx + 1);
                a1 += v * wc0[k];
                a2 += v * wc1[k];
            }
        }
    }

    __shared__ float s1[256];
    __shared__ float s2[256];
    s1[threadIdx.x] = a1; s2[threadIdx.x] = a2;
    __syncthreads();

    if (threadIdx.x < 32) {
        float t1 = 0.f, t2 = 0.f;
#pragma unroll
        for (int g = 0; g < 8; ++g) { t1 += s1[g * 32 + x]; t2 += s2[g * 32 + x]; }
        t1 = fmaxf(t1 + b0[0], 0.f);
        t2 = fmaxf(t2 + b1[0], 0.f);
        c1[b * 1024 + y * 32 + x] = t1;
        c2[b * 1024 + y * 32 + x] = t2;
    }
}

// ---------------------------------------------------------------------------
// Kernel C: per-batch means of m2 and c2, then
// total_map = m1 * mean(m2) + c1 * mean(c2)   [8,32,32]
// ---------------------------------------------------------------------------
__global__ __launch_bounds__(1024)
void finalize_map_kernel(const float* __restrict__ m1, const float* __restrict__ m2,
                         const float* __restrict__ c1, const float* __restrict__ c2,
                         float* __restrict__ tmap) {
    int b = blockIdx.x;
    int t = threadIdx.x;
    float v2 = m2[b * 1024 + t];
    float w2 = c2[b * 1024 + t];

    __shared__ float sm[1024];
    __shared__ float sc[1024];
    sm[t] = v2; sc[t] = w2;
    __syncthreads();
    for (int s = 512; s > 0; s >>= 1) {
        if (t < s) { sm[t] += sm[t + s]; sc[t] += sc[t + s]; }
        __syncthreads();
    }
    float mm = sm[0] * (1.f / 1024.f);
    float mc = sc[0] * (1.f / 1024.f);
    tmap[b * 1024 + t] = m1[b * 1024 + t] * mm + c1[b * 1024 + t] * mc;
}

// ---------------------------------------------------------------------------
// Kernel D: out = x + nearest_resize(total_map).  One instantiation per level.
// float4 streaming; map (32KB) stays in cache. idx math is all shifts/masks.
// ---------------------------------------------------------------------------
template<int LOG2S>
__device__ __forceinline__ int map_coord(int p) {
    if constexpr (LOG2S >= 5) return p >> (LOG2S - 5);
    else                      return p << (5 - LOG2S);
}

template<int S, int LOG2S>
__global__ __launch_bounds__(256)
void add_maps_kernel(const float4* __restrict__ x, float4* __restrict__ out,
                     const float* __restrict__ tmap) {
    int idx = blockIdx.x * 256 + threadIdx.x;   // grid sized exactly
    constexpr int W4 = S / 4;

    int xq  = idx & (W4 - 1);
    int row = idx >> (LOG2S - 2);   // global row = (b*256 + c)*S + y
    int y   = row & (S - 1);
    int bc  = row >> LOG2S;
    int b   = bc >> 8;              // C = 256

    int my = map_coord<LOG2S>(y);
    const float* mrow = tmap + b * 1024 + my * 32;

    int xp = xq * 4;
    float4 v = x[idx];
    float4 r;
    r.x = v.x + mrow[map_coord<LOG2S>(xp + 0)];
    r.y = v.y + mrow[map_coord<LOG2S>(xp + 1)];
    r.z = v.z + mrow[map_coord<LOG2S>(xp + 2)];
    r.w = v.w + mrow[map_coord<LOG2S>(xp + 3)];
    out[idx] = r;
}

// ---------------------------------------------------------------------------
extern "C" void kernel_launch(void* const* d_in, const int* in_sizes, int n_in,
                              void* d_out, int out_size, void* d_ws, size_t ws_size,
                              hipStream_t stream) {
    const float* x0 = (const float*)d_in[0];
    const float* x1 = (const float*)d_in[1];
    const float* x2 = (const float*)d_in[2];
    const float* x3 = (const float*)d_in[3];
    const float* x4 = (const float*)d_in[4];
    const float* com_w0 = (const float*)d_in[5];
    const float* com_b0 = (const float*)d_in[6];
    const float* com_w1 = (const float*)d_in[7];
    const float* com_b1 = (const float*)d_in[8];
    const float* en_w0  = (const float*)d_in[9];
    const float* en_b0  = (const float*)d_in[10];
    const float* en_w1  = (const float*)d_in[11];
    const float* en_b1  = (const float*)d_in[12];

    float* out = (float*)d_out;
    float* ws  = (float*)d_ws;
    float* m1   = ws;            // [8*1024]
    float* m2   = ws + 8192;
    float* c1   = ws + 16384;
    float* c2   = ws + 24576;
    float* tmap = ws + 32768;

    dot_pool_kernel<<<256, 512, 0, stream>>>(x0, com_w0, com_b0, com_w1, com_b1, m1, m2);
    conv3x3_kernel<<<dim3(32, 8), 256, 0, stream>>>(x2, en_w0, en_b0, en_w1, en_b1, c1, c2);
    finalize_map_kernel<<<8, 1024, 0, stream>>>(m1, m2, c1, c2, tmap);

    // Output layout: 5 levels concatenated flat in return order.
    const long long o0 = 0;
    const long long o1 = o0 + 8LL * 256 * 128 * 128;  // 33,554,432
    const long long o2 = o1 + 8LL * 256 * 64 * 64;    // 41,943,040
    const long long o3 = o2 + 8LL * 256 * 32 * 32;    // 44,040,192
    const long long o4 = o3 + 8LL * 256 * 16 * 16;    // 44,564,480

    add_maps_kernel<128, 7><<<32768, 256, 0, stream>>>((const float4*)x0, (float4*)(out + o0), tmap);
    add_maps_kernel<64, 6><<<8192, 256, 0, stream>>>((const float4*)x1, (float4*)(out + o1), tmap);
    add_maps_kernel<32, 5><<<2048, 256, 0, stream>>>((const float4*)x2, (float4*)(out + o2), tmap);
    add_maps_kernel<16, 4><<<512, 256, 0, stream>>>((const float4*)x3, (float4*)(out + o3), tmap);
    add_maps_kernel<8, 3><<<128, 256, 0, stream>>>((const float4*)x4, (float4*)(out + o4), tmap);
}

// Round 2
// 96.084 us; speedup vs baseline: 1.1927x; 1.1927x over previous
//
#include <hip/hip_runtime.h>

#define BATCH 8
#define CH 256

// ---------------------------------------------------------------------------
// Fused kernel 1: blocks [0,256) do the dot+pool path on x0 (1x1 convs commute
// with the 4x4 avg pool, so dot at full res then pool); blocks [256,512) do
// the two 3x3 convs (256ch->1) on x2. Branch is block-uniform.
// 512 threads per block.
// ---------------------------------------------------------------------------
__global__ __launch_bounds__(512)
void map_partial_kernel(const float* __restrict__ x0, const float* __restrict__ x2,
                        const float* __restrict__ cw0, const float* __restrict__ cb0,
                        const float* __restrict__ cw1, const float* __restrict__ cb1,
                        const float* __restrict__ ew0, const float* __restrict__ eb0,
                        const float* __restrict__ ew1, const float* __restrict__ eb1,
                        float* __restrict__ m1, float* __restrict__ m2,
                        float* __restrict__ c1, float* __restrict__ c2) {
    __shared__ float s1[512];
    __shared__ float s2[512];
    int t = threadIdx.x;

    if (blockIdx.x < 256) {
        // ---- dot + 4x4 pool on x0 [8,256,128,128] -> m1,m2 [8,32,32] ----
        int blk = blockIdx.x;
        int b   = blk >> 5;
        int p   = (blk & 31) * 512 + t;      // 4 image rows per block

        const float* xb = x0 + b * (CH * 16384) + p;
        float a1 = 0.f, a2 = 0.f;
#pragma unroll 16
        for (int c = 0; c < CH; ++c) {
            float v = xb[c * 16384];
            a1 += v * cw0[c];
            a2 += v * cw1[c];
        }
        s1[t] = a1; s2[t] = a2;
        __syncthreads();

        if (t < 32) {
            float t1 = 0.f, t2 = 0.f;
#pragma unroll
            for (int r = 0; r < 4; ++r)
#pragma unroll
                for (int j = 0; j < 4; ++j) {
                    t1 += s1[r * 128 + t * 4 + j];
                    t2 += s2[r * 128 + t * 4 + j];
                }
            int h = blk & 31;
            m1[b * 1024 + h * 32 + t] = fmaxf(t1 * 0.0625f + cb0[0], 0.f);
            m2[b * 1024 + h * 32 + t] = fmaxf(t2 * 0.0625f + cb1[0], 0.f);
        }
    } else {
        // ---- two 3x3 convs + relu on x2 [8,256,32,32] -> c1,c2 [8,32,32] ----
        int blk = blockIdx.x - 256;
        int y = blk & 31;
        int b = blk >> 5;
        int x  = t & 31;
        int cg = t >> 5;                      // 16 groups of 16 channels

        const float* xb = x2 + b * (CH * 1024);
        float a1 = 0.f, a2 = 0.f;

        for (int ci = 0; ci < 16; ++ci) {
            int c = cg * 16 + ci;
            const float* xc  = xb + c * 1024;
            const float* wc0 = ew0 + c * 9;
            const float* wc1 = ew1 + c * 9;
#pragma unroll
            for (int dy = -1; dy <= 1; ++dy) {
                int yy = y + dy;
                bool yok = (unsigned)yy < 32u;
#pragma unroll
                for (int dx = -1; dx <= 1; ++dx) {
                    int xx = x + dx;
                    bool ok = yok && ((unsigned)xx < 32u);
                    float v = ok ? xc[yy * 32 + xx] : 0.f;
                    int k = (dy + 1) * 3 + (dx + 1);
                    a1 += v * wc0[k];
                    a2 += v * wc1[k];
                }
            }
        }
        s1[t] = a1; s2[t] = a2;
        __syncthreads();

        if (t < 32) {
            float t1 = 0.f, t2 = 0.f;
#pragma unroll
            for (int g = 0; g < 16; ++g) { t1 += s1[g * 32 + x]; t2 += s2[g * 32 + x]; }
            c1[b * 1024 + y * 32 + x] = fmaxf(t1 + eb0[0], 0.f);
            c2[b * 1024 + y * 32 + x] = fmaxf(t2 + eb1[0], 0.f);
        }
    }
}

// ---------------------------------------------------------------------------
// Kernel 2: per-batch means of m2/c2 (wave shuffle reduce), then
// tmap = m1*mean(m2) + c1*mean(c2).  8 blocks x 256 threads, float4.
// ---------------------------------------------------------------------------
__global__ __launch_bounds__(256)
void finalize_map_kernel(const float4* __restrict__ m1, const float4* __restrict__ m2,
                         const float4* __restrict__ c1, const float4* __restrict__ c2,
                         float4* __restrict__ tmap) {
    int b = blockIdx.x;
    int t = threadIdx.x;
    float4 v2 = m2[b * 256 + t];
    float4 w2 = c2[b * 256 + t];
    float sm = v2.x + v2.y + v2.z + v2.w;
    float sc = w2.x + w2.y + w2.z + w2.w;
#pragma unroll
    for (int off = 32; off > 0; off >>= 1) {
        sm += __shfl_down(sm, off);
        sc += __shfl_down(sc, off);
    }
    __shared__ float rm[4];
    __shared__ float rc[4];
    int wave = t >> 6, lane = t & 63;
    if (lane == 0) { rm[wave] = sm; rc[wave] = sc; }
    __syncthreads();
    float mm = (rm[0] + rm[1] + rm[2] + rm[3]) * (1.f / 1024.f);
    float mc = (rc[0] + rc[1] + rc[2] + rc[3]) * (1.f / 1024.f);

    float4 a1 = m1[b * 256 + t];
    float4 a2 = c1[b * 256 + t];
    float4 r;
    r.x = a1.x * mm + a2.x * mc;
    r.y = a1.y * mm + a2.y * mc;
    r.z = a1.z * mm + a2.z * mc;
    r.w = a1.w * mm + a2.w * mc;
    tmap[b * 256 + t] = r;
}

// ---------------------------------------------------------------------------
// Kernel 3: fused out = x + nearest_resize(tmap) for ALL five levels.
// Level boundaries (in float4) are multiples of 256, so the level branch is
// block-uniform. One launch, perfect packing, no inter-level drains.
// ---------------------------------------------------------------------------
template<int LOG2S>
__device__ __forceinline__ int map_coord(int p) {
    if constexpr (LOG2S >= 5) return p >> (LOG2S - 5);
    else                      return p << (5 - LOG2S);
}

template<int S, int LOG2S>
__device__ __forceinline__ void add_level(const float4* __restrict__ x,
                                          float4* __restrict__ out,
                                          const float* __restrict__ tmap, int F) {
    constexpr int W4 = S / 4;
    int xq  = F & (W4 - 1);
    int row = F >> (LOG2S - 2);     // (b*256 + c)*S + y
    int y   = row & (S - 1);
    int b   = (row >> LOG2S) >> 8;  // C = 256

    int my = map_coord<LOG2S>(y);
    const float* mrow = tmap + b * 1024 + my * 32;

    int xp = xq * 4;
    float4 v = x[F];
    float4 r;
    r.x = v.x + mrow[map_coord<LOG2S>(xp + 0)];
    r.y = v.y + mrow[map_coord<LOG2S>(xp + 1)];
    r.z = v.z + mrow[map_coord<LOG2S>(xp + 2)];
    r.w = v.w + mrow[map_coord<LOG2S>(xp + 3)];
    out[F] = r;
}

// float4 level boundaries
#define E0 8388608
#define E1 10485760
#define E2 11010048
#define E3 11141120
#define E4 11173888

__global__ __launch_bounds__(256)
void add_all_kernel(const float4* __restrict__ x0, const float4* __restrict__ x1,
                    const float4* __restrict__ x2, const float4* __restrict__ x3,
                    const float4* __restrict__ x4, float4* __restrict__ out,
                    const float* __restrict__ tmap) {
    int g = blockIdx.x * 256 + threadIdx.x;
    if (g < E0)      add_level<128, 7>(x0, out,      tmap, g);
    else if (g < E1) add_level< 64, 6>(x1, out + E0, tmap, g - E0);
    else if (g < E2) add_level< 32, 5>(x2, out + E1, tmap, g - E1);
    else if (g < E3) add_level< 16, 4>(x3, out + E2, tmap, g - E2);
    else             add_level<  8, 3>(x4, out + E3, tmap, g - E3);
}

// ---------------------------------------------------------------------------
extern "C" void kernel_launch(void* const* d_in, const int* in_sizes, int n_in,
                              void* d_out, int out_size, void* d_ws, size_t ws_size,
                              hipStream_t stream) {
    const float* x0 = (const float*)d_in[0];
    const float* x1 = (const float*)d_in[1];
    const float* x2 = (const float*)d_in[2];
    const float* x3 = (const float*)d_in[3];
    const float* x4 = (const float*)d_in[4];
    const float* com_w0 = (const float*)d_in[5];
    const float* com_b0 = (const float*)d_in[6];
    const float* com_w1 = (const float*)d_in[7];
    const float* com_b1 = (const float*)d_in[8];
    const float* en_w0  = (const float*)d_in[9];
    const float* en_b0  = (const float*)d_in[10];
    const float* en_w1  = (const float*)d_in[11];
    const float* en_b1  = (const float*)d_in[12];

    float* out = (float*)d_out;
    float* ws  = (float*)d_ws;
    float* m1   = ws;            // [8*1024] each
    float* m2   = ws + 8192;
    float* c1   = ws + 16384;
    float* c2   = ws + 24576;
    float* tmap = ws + 32768;

    map_partial_kernel<<<512, 512, 0, stream>>>(
        x0, x2, com_w0, com_b0, com_w1, com_b1,
        en_w0, en_b0, en_w1, en_b1, m1, m2, c1, c2);

    finalize_map_kernel<<<8, 256, 0, stream>>>(
        (const float4*)m1, (const float4*)m2,
        (const float4*)c1, (const float4*)c2, (float4*)tmap);

    add_all_kernel<<<E4 / 256, 256, 0, stream>>>(
        (const float4*)x0, (const float4*)x1, (const float4*)x2,
        (const float4*)x3, (const float4*)x4, (float4*)out, tmap);
}

// Round 3
// 89.144 us; speedup vs baseline: 1.2856x; 1.0779x over previous
//
#include <hip/hip_runtime.h>

#define BATCH 8
#define CH 256

typedef float f4_t __attribute__((ext_vector_type(4)));

// ---------------------------------------------------------------------------
// Fused kernel 1: blocks [0,256) do the dot+pool path on x0 (1x1 convs commute
// with the 4x4 avg pool, so dot at full res then pool); blocks [256,512) do
// the two 3x3 convs (256ch->1) on x2. Branch is block-uniform.
// 512 threads per block.  (unchanged from round 2)
// ---------------------------------------------------------------------------
__global__ __launch_bounds__(512)
void map_partial_kernel(const float* __restrict__ x0, const float* __restrict__ x2,
                        const float* __restrict__ cw0, const float* __restrict__ cb0,
                        const float* __restrict__ cw1, const float* __restrict__ cb1,
                        const float* __restrict__ ew0, const float* __restrict__ eb0,
                        const float* __restrict__ ew1, const float* __restrict__ eb1,
                        float* __restrict__ m1, float* __restrict__ m2,
                        float* __restrict__ c1, float* __restrict__ c2) {
    __shared__ float s1[512];
    __shared__ float s2[512];
    int t = threadIdx.x;

    if (blockIdx.x < 256) {
        // ---- dot + 4x4 pool on x0 [8,256,128,128] -> m1,m2 [8,32,32] ----
        int blk = blockIdx.x;
        int b   = blk >> 5;
        int p   = (blk & 31) * 512 + t;      // 4 image rows per block

        const float* xb = x0 + b * (CH * 16384) + p;
        float a1 = 0.f, a2 = 0.f;
#pragma unroll 16
        for (int c = 0; c < CH; ++c) {
            float v = xb[c * 16384];
            a1 += v * cw0[c];
            a2 += v * cw1[c];
        }
        s1[t] = a1; s2[t] = a2;
        __syncthreads();

        if (t < 32) {
            float t1 = 0.f, t2 = 0.f;
#pragma unroll
            for (int r = 0; r < 4; ++r)
#pragma unroll
                for (int j = 0; j < 4; ++j) {
                    t1 += s1[r * 128 + t * 4 + j];
                    t2 += s2[r * 128 + t * 4 + j];
                }
            int h = blk & 31;
            m1[b * 1024 + h * 32 + t] = fmaxf(t1 * 0.0625f + cb0[0], 0.f);
            m2[b * 1024 + h * 32 + t] = fmaxf(t2 * 0.0625f + cb1[0], 0.f);
        }
    } else {
        // ---- two 3x3 convs + relu on x2 [8,256,32,32] -> c1,c2 [8,32,32] ----
        int blk = blockIdx.x - 256;
        int y = blk & 31;
        int b = blk >> 5;
        int x  = t & 31;
        int cg = t >> 5;                      // 16 groups of 16 channels

        const float* xb = x2 + b * (CH * 1024);
        float a1 = 0.f, a2 = 0.f;

        for (int ci = 0; ci < 16; ++ci) {
            int c = cg * 16 + ci;
            const float* xc  = xb + c * 1024;
            const float* wc0 = ew0 + c * 9;
            const float* wc1 = ew1 + c * 9;
#pragma unroll
            for (int dy = -1; dy <= 1; ++dy) {
                int yy = y + dy;
                bool yok = (unsigned)yy < 32u;
#pragma unroll
                for (int dx = -1; dx <= 1; ++dx) {
                    int xx = x + dx;
                    bool ok = yok && ((unsigned)xx < 32u);
                    float v = ok ? xc[yy * 32 + xx] : 0.f;
                    int k = (dy + 1) * 3 + (dx + 1);
                    a1 += v * wc0[k];
                    a2 += v * wc1[k];
                }
            }
        }
        s1[t] = a1; s2[t] = a2;
        __syncthreads();

        if (t < 32) {
            float t1 = 0.f, t2 = 0.f;
#pragma unroll
            for (int g = 0; g < 16; ++g) { t1 += s1[g * 32 + x]; t2 += s2[g * 32 + x]; }
            c1[b * 1024 + y * 32 + x] = fmaxf(t1 + eb0[0], 0.f);
            c2[b * 1024 + y * 32 + x] = fmaxf(t2 + eb1[0], 0.f);
        }
    }
}

// ---------------------------------------------------------------------------
// Kernel 2: per-batch means of m2/c2 (wave shuffle reduce), then
// tmap = m1*mean(m2) + c1*mean(c2).  8 blocks x 256 threads, float4.
// (unchanged from round 2)
// ---------------------------------------------------------------------------
__global__ __launch_bounds__(256)
void finalize_map_kernel(const float4* __restrict__ m1, const float4* __restrict__ m2,
                         const float4* __restrict__ c1, const float4* __restrict__ c2,
                         float4* __restrict__ tmap) {
    int b = blockIdx.x;
    int t = threadIdx.x;
    float4 v2 = m2[b * 256 + t];
    float4 w2 = c2[b * 256 + t];
    float sm = v2.x + v2.y + v2.z + v2.w;
    float sc = w2.x + w2.y + w2.z + w2.w;
#pragma unroll
    for (int off = 32; off > 0; off >>= 1) {
        sm += __shfl_down(sm, off);
        sc += __shfl_down(sc, off);
    }
    __shared__ float rm[4];
    __shared__ float rc[4];
    int wave = t >> 6, lane = t & 63;
    if (lane == 0) { rm[wave] = sm; rc[wave] = sc; }
    __syncthreads();
    float mm = (rm[0] + rm[1] + rm[2] + rm[3]) * (1.f / 1024.f);
    float mc = (rc[0] + rc[1] + rc[2] + rc[3]) * (1.f / 1024.f);

    float4 a1 = m1[b * 256 + t];
    float4 a2 = c1[b * 256 + t];
    float4 r;
    r.x = a1.x * mm + a2.x * mc;
    r.y = a1.y * mm + a2.y * mc;
    r.z = a1.z * mm + a2.z * mc;
    r.w = a1.w * mm + a2.w * mc;
    tmap[b * 256 + t] = r;
}

// ---------------------------------------------------------------------------
// Kernel 3: fused out = x + nearest_resize(tmap) for ALL five levels.
// NEW this round: non-temporal stores for `out` so the 178.8 MB output stream
// does NOT allocate in the 256 MB Infinity Cache. All inputs (178.8 MB total)
// then stay L3-resident across kernels AND across graph replays; in steady
// state every input read is an L3 hit and HBM sees only the NT write stream.
// ---------------------------------------------------------------------------
template<int LOG2S>
__device__ __forceinline__ int map_coord(int p) {
    if constexpr (LOG2S >= 5) return p >> (LOG2S - 5);
    else                      return p << (5 - LOG2S);
}

template<int S, int LOG2S>
__device__ __forceinline__ void add_level(const f4_t* __restrict__ x,
                                          f4_t* __restrict__ out,
                                          const float* __restrict__ tmap, int F) {
    constexpr int W4 = S / 4;
    int xq  = F & (W4 - 1);
    int row = F >> (LOG2S - 2);     // (b*256 + c)*S + y
    int y   = row & (S - 1);
    int b   = (row >> LOG2S) >> 8;  // C = 256

    int my = map_coord<LOG2S>(y);
    const float* mrow = tmap + b * 1024 + my * 32;

    int xp = xq * 4;
    f4_t v = x[F];                  // normal load: allocate in L3 for reuse
    f4_t r;
    r.x = v.x + mrow[map_coord<LOG2S>(xp + 0)];
    r.y = v.y + mrow[map_coord<LOG2S>(xp + 1)];
    r.z = v.z + mrow[map_coord<LOG2S>(xp + 2)];
    r.w = v.w + mrow[map_coord<LOG2S>(xp + 3)];
    __builtin_nontemporal_store(r, out + F);   // bypass cache allocation
}

// float4 level boundaries
#define E0 8388608
#define E1 10485760
#define E2 11010048
#define E3 11141120
#define E4 11173888

__global__ __launch_bounds__(256)
void add_all_kernel(const f4_t* __restrict__ x0, const f4_t* __restrict__ x1,
                    const f4_t* __restrict__ x2, const f4_t* __restrict__ x3,
                    const f4_t* __restrict__ x4, f4_t* __restrict__ out,
                    const float* __restrict__ tmap) {
    int g = blockIdx.x * 256 + threadIdx.x;
    if (g < E0)      add_level<128, 7>(x0, out,      tmap, g);
    else if (g < E1) add_level< 64, 6>(x1, out + E0, tmap, g - E0);
    else if (g < E2) add_level< 32, 5>(x2, out + E1, tmap, g - E1);
    else if (g < E3) add_level< 16, 4>(x3, out + E2, tmap, g - E2);
    else             add_level<  8, 3>(x4, out + E3, tmap, g - E3);
}

// ---------------------------------------------------------------------------
extern "C" void kernel_launch(void* const* d_in, const int* in_sizes, int n_in,
                              void* d_out, int out_size, void* d_ws, size_t ws_size,
                              hipStream_t stream) {
    const float* x0 = (const float*)d_in[0];
    const float* x1 = (const float*)d_in[1];
    const float* x2 = (const float*)d_in[2];
    const float* x3 = (const float*)d_in[3];
    const float* x4 = (const float*)d_in[4];
    const float* com_w0 = (const float*)d_in[5];
    const float* com_b0 = (const float*)d_in[6];
    const float* com_w1 = (const float*)d_in[7];
    const float* com_b1 = (const float*)d_in[8];
    const float* en_w0  = (const float*)d_in[9];
    const float* en_b0  = (const float*)d_in[10];
    const float* en_w1  = (const float*)d_in[11];
    const float* en_b1  = (const float*)d_in[12];

    float* out = (float*)d_out;
    float* ws  = (float*)d_ws;
    float* m1   = ws;            // [8*1024] each
    float* m2   = ws + 8192;
    float* c1   = ws + 16384;
    float* c2   = ws + 24576;
    float* tmap = ws + 32768;

    map_partial_kernel<<<512, 512, 0, stream>>>(
        x0, x2, com_w0, com_b0, com_w1, com_b1,
        en_w0, en_b0, en_w1, en_b1, m1, m2, c1, c2);

    finalize_map_kernel<<<8, 256, 0, stream>>>(
        (const float4*)m1, (const float4*)m2,
        (const float4*)c1, (const float4*)c2, (float4*)tmap);

    add_all_kernel<<<E4 / 256, 256, 0, stream>>>(
        (const f4_t*)x0, (const f4_t*)x1, (const f4_t*)x2,
        (const f4_t*)x3, (const f4_t*)x4, (f4_t*)out, tmap);
}